// Round 5
// baseline (365.996 us; speedup 1.0000x reference)
//
#include <hip/hip_runtime.h>
#include <hip/hip_bf16.h>
#include <math.h>

#define S 2048
#define D 512
#define H 8
#define KH 2
#define DH 64
#define G 4
#define CBS 32
#define NSEL 8
#define WIN 128
#define NC 64
#define CDIM 2048

typedef __attribute__((ext_vector_type(8))) short bf16x8_t;
typedef __attribute__((ext_vector_type(4))) float f32x4_t;

static __device__ __forceinline__ unsigned short f2bf(float f) {
    union { float f; unsigned int u; } v; v.f = f;
    unsigned int r = (v.u + 0x7FFFu + ((v.u >> 16) & 1u)) >> 16;
    return (unsigned short)r;
}
static __device__ __forceinline__ float bf2f(unsigned short h) {
    union { unsigned int u; float f; } v; v.u = ((unsigned int)h) << 16;
    return v.f;
}
static __device__ __forceinline__ float bflo(unsigned int u) {
    union { unsigned int u; float f; } v; v.u = u << 16; return v.f;
}
static __device__ __forceinline__ float bfhi(unsigned int u) {
    union { unsigned int u; float f; } v; v.u = u & 0xffff0000u; return v.f;
}
static __device__ __forceinline__ unsigned int cvtpk_bf16(float lo, float hi) {
    unsigned int r;
    asm("v_cvt_pk_bf16_f32 %0, %1, %2" : "=v"(r) : "v"(lo), "v"(hi));
    return r;
}

// ---------------- RMSNorm -> x bf16 ----------------
__global__ __launch_bounds__(256) void k_rmsnorm(const float* __restrict__ inp,
                                                 const float* __restrict__ w,
                                                 unsigned short* __restrict__ xbf) {
    int s = blockIdx.x; int t = threadIdx.x;
    const float* row = inp + (size_t)s * D;
    float a = row[t], b = row[t + 256];
    float ss = a * a + b * b;
    for (int off = 32; off; off >>= 1) ss += __shfl_xor(ss, off);
    __shared__ float red[4];
    if ((t & 63) == 0) red[t >> 6] = ss;
    __syncthreads();
    float tot = red[0] + red[1] + red[2] + red[3];
    float inv = rsqrtf(tot / (float)D + 1.1920929e-07f);
    xbf[(size_t)s * D + t]       = f2bf(a * inv * w[t]);
    xbf[(size_t)s * D + t + 256] = f2bf(b * inv * w[t + 256]);
}

// ---------------- generic bf16 MFMA GEMM 64x64 tile ----------------
// A bf16; B weights f32, converted during LDS staging.
// MODE 0: qkv scatter. MODE 1: +bias, relu, bf16 (hid). MODE 2: fp32 out.
// MODE 3: +bias, scatter into ck/cv rows (replaces k_mlp2).
template<int MODE>
__global__ __launch_bounds__(256) void k_gemm(
    const unsigned short* __restrict__ A,
    const float* __restrict__ B0,
    const float* __restrict__ B1,
    const float* __restrict__ bias0, const float* __restrict__ bias1,
    int M, int N, int K,
    float* __restrict__ q, float* __restrict__ kk, float* __restrict__ vv,
    unsigned short* __restrict__ hid, float* __restrict__ outC)
{
    __shared__ __align__(16) unsigned short As[64][40];
    __shared__ __align__(16) unsigned short Bs[64][40];
    int t = threadIdx.x;
    int m0 = blockIdx.y * 64, n0 = blockIdx.x * 64;
    const float* W = B0;
    const float* bias = bias0;
    if ((MODE == 1 || MODE == 3) && blockIdx.y >= 2) { W = B1; bias = bias1; }
    int wave = t >> 6, lane = t & 63;
    int mh = wave & 1, nh = wave >> 1;
    f32x4_t acc[2][2] = {};
    int ar = t >> 2, ac = (t & 3) * 8;
    int bk = t >> 3, bn = (t & 7) * 8;
    int arow_l = lane & 15, kcol = (lane >> 4) * 8;
    for (int k0 = 0; k0 < K; k0 += 32) {
        __syncthreads();
        *(uint4*)&As[ar][ac] = *(const uint4*)&A[(size_t)(m0 + ar) * K + k0 + ac];
        const float4* wrow = (const float4*)&W[(size_t)(k0 + bk) * N + n0 + bn];
        float4 w0 = wrow[0], w1 = wrow[1];
        unsigned short bp[8];
        bp[0] = f2bf(w0.x); bp[1] = f2bf(w0.y); bp[2] = f2bf(w0.z); bp[3] = f2bf(w0.w);
        bp[4] = f2bf(w1.x); bp[5] = f2bf(w1.y); bp[6] = f2bf(w1.z); bp[7] = f2bf(w1.w);
        #pragma unroll
        for (int j = 0; j < 8; ++j) Bs[bn + j][bk] = bp[j];
        __syncthreads();
        bf16x8_t a0 = *(const bf16x8_t*)&As[mh * 32 + arow_l][kcol];
        bf16x8_t a1 = *(const bf16x8_t*)&As[mh * 32 + 16 + arow_l][kcol];
        bf16x8_t b0v = *(const bf16x8_t*)&Bs[nh * 32 + arow_l][kcol];
        bf16x8_t b1v = *(const bf16x8_t*)&Bs[nh * 32 + 16 + arow_l][kcol];
        acc[0][0] = __builtin_amdgcn_mfma_f32_16x16x32_bf16(a0, b0v, acc[0][0], 0, 0, 0);
        acc[0][1] = __builtin_amdgcn_mfma_f32_16x16x32_bf16(a0, b1v, acc[0][1], 0, 0, 0);
        acc[1][0] = __builtin_amdgcn_mfma_f32_16x16x32_bf16(a1, b0v, acc[1][0], 0, 0, 0);
        acc[1][1] = __builtin_amdgcn_mfma_f32_16x16x32_bf16(a1, b1v, acc[1][1], 0, 0, 0);
    }
    #pragma unroll
    for (int mi = 0; mi < 2; ++mi)
    #pragma unroll
    for (int ni = 0; ni < 2; ++ni)
    #pragma unroll
    for (int r = 0; r < 4; ++r) {
        int gm = m0 + mh * 32 + mi * 16 + (lane >> 4) * 4 + r;
        int gn = n0 + nh * 32 + ni * 16 + (lane & 15);
        float val = acc[mi][ni][r];
        if (MODE == 0) {
            if (gn < 512)      q [((gn >> 6) * S + gm) * DH + (gn & 63)] = val;
            else if (gn < 640) kk[(((gn - 512) >> 6) * S + gm) * DH + ((gn - 512) & 63)] = val;
            else               vv[(((gn - 640) >> 6) * S + gm) * DH + ((gn - 640) & 63)] = val;
        } else if (MODE == 1) {
            float h = val + bias[gn]; if (h < 0.f) h = 0.f;
            hid[(size_t)gm * N + gn] = f2bf(h);
        } else if (MODE == 3) {
            float h = val + bias[gn];
            float* dst = (gm >= 128) ? kk : q;   // cv : ck
            int kh2 = (gm >> 6) & 1, nc2 = gm & 63;
            dst[(kh2 * 65 + 1 + nc2) * 64 + gn] = h;
        } else {
            outC[(size_t)gm * N + gn] = val;
        }
    }
}

// ---------------- kb/vb builder ----------------
__global__ void k_build_kbvb(const float* __restrict__ kbuf, const float* __restrict__ vbuf,
                             const float* __restrict__ k_pos, const float* __restrict__ v_pos,
                             unsigned short* __restrict__ kbvb) {
    int idx = blockIdx.x * 256 + threadIdx.x;   // 256*2048
    int r = idx >> 11, c = idx & 2047;
    int tt = c >> 6, dh = c & 63;
    int path = r >> 7, kh = (r >> 6) & 1, nc = r & 63;
    const float* src = path ? vbuf : kbuf;
    const float* pos = path ? v_pos : k_pos;
    float val = src[((kh * S) + nc * 32 + tt) * DH + dh] + pos[(kh * CBS + tt) * DH + dh];
    kbvb[idx] = f2bf(val);
}

// ---------------- mem_kv -> ck/cv row 0 ----------------
__global__ void k_mem_init(const float* __restrict__ mem_kv, float* __restrict__ ck, float* __restrict__ cv) {
    int t = threadIdx.x;
    int path = t >> 7, kh = (t >> 6) & 1, d = t & 63;
    float* dst = path ? cv : ck;
    dst[kh * 65 * 64 + d] = mem_kv[path * (KH * DH) + kh * DH + d];
}

// ---------------- RoPE tables ----------------
__global__ void k_rope_table(float* __restrict__ ct, float* __restrict__ st) {
    int idx = blockIdx.x * 256 + threadIdx.x;   // 2048*32
    int s = idx >> 5, p = idx & 31;
    float inv = powf(10000.0f, -(float)p / 32.0f);
    float fr = (float)s * inv;
    ct[idx] = cosf(fr); st[idx] = sinf(fr);
}

// ------- fused rope(q)*scale, rope(k), convert(v) -> bf16 -------
// q rows get the 1/8 attention scale baked in (swattn consumes scaled q).
__global__ __launch_bounds__(256) void k_ropeprep(
    const float* __restrict__ qb, const float* __restrict__ kbuf, const float* __restrict__ vbuf,
    const float* __restrict__ ct, const float* __restrict__ st,
    unsigned short* __restrict__ qr16, unsigned short* __restrict__ kr16,
    unsigned short* __restrict__ v16)
{
    int idx = blockIdx.x * 256 + threadIdx.x;   // (H*S + 2*KH*S) * 32
    int row = idx >> 5, p = idx & 31;
    const int QR = H * S, KR = KH * S;
    const float* src; unsigned short* dst; bool dorope; float sc = 1.f;
    if (row < QR)           { src = qb   + (size_t)row * 64;             dst = qr16 + (size_t)row * 64;             dorope = true; sc = 0.125f; }
    else if (row < QR + KR) { src = kbuf + (size_t)(row - QR) * 64;      dst = kr16 + (size_t)(row - QR) * 64;      dorope = true; }
    else                    { src = vbuf + (size_t)(row - QR - KR) * 64; dst = v16  + (size_t)(row - QR - KR) * 64; dorope = false; }
    float x0 = src[2 * p], x1 = src[2 * p + 1];
    if (dorope) {
        int s = row & (S - 1);
        float c = ct[s * 32 + p], sn = st[s * 32 + p];
        float y0 = (x0 * c - x1 * sn) * sc, y1 = (x1 * c + x0 * sn) * sc;
        dst[2 * p] = f2bf(y0); dst[2 * p + 1] = f2bf(y1);
    } else {
        dst[2 * p] = f2bf(x0); dst[2 * p + 1] = f2bf(x1);
    }
}

// ---------------- compressed attention + importance + top-8 ----------------
__global__ __launch_bounds__(256) void k_cattn(
    const float* __restrict__ q, const float* __restrict__ ck, const float* __restrict__ cv,
    float* __restrict__ c_out, int* __restrict__ sel)
{
    int kh = blockIdx.x >> 8, sc = blockIdx.x & 255;   // grid = 2*256
    int s_base = sc * 8;
    __shared__ float ckT[64][65];   // [d][j]
    __shared__ float cvL[64][66];   // [j][d]
    __shared__ float qL[4][64];
    __shared__ float simL[4][64];
    int t = threadIdx.x;
    for (int idx = t; idx < 4096; idx += 256) {
        int j = idx >> 6, d = idx & 63;
        ckT[d][j] = ck[(kh * 65 + j) * 64 + d];
        cvL[j][d] = cv[(kh * 65 + j) * 64 + d];
    }
    int g = t >> 6, lane = t & 63;
    for (int si = 0; si < 8; ++si) {
        int s = s_base + si;
        __syncthreads();
        qL[g][lane] = q[((kh * G + g) * S + s) * DH + lane];
        __syncthreads();
        int j = lane;
        bool valid = (j == 0) || (s >= j * 32);
        float sim = 0.f;
        #pragma unroll 8
        for (int d = 0; d < 64; ++d) sim += qL[g][d] * ckT[d][j];
        sim *= 0.125f;
        float simm = valid ? sim : -INFINITY;
        simL[g][j] = simm;
        float m = simm;
        for (int off = 32; off; off >>= 1) m = fmaxf(m, __shfl_xor(m, off));
        float p = valid ? __expf(simm - m) : 0.f;
        float den = p;
        for (int off = 32; off; off >>= 1) den += __shfl_xor(den, off);
        float pn = p / den;
        float acc = 0.f;
        #pragma unroll 8
        for (int jj = 0; jj < 64; ++jj)
            acc += __shfl(pn, jj) * cvL[jj][lane];
        c_out[((kh * G + g) * S + s) * DH + lane] = acc;
        __syncthreads();
        if (g == 0) {
            int l = lane;
            float lv = -INFINITY;
            if (l < 63 && s >= (l + 1) * 32)
                lv = 0.25f * (simL[0][l + 1] + simL[1][l + 1] + simL[2][l + 1] + simL[3][l + 1]);
            float mm = lv;
            for (int off = 32; off; off >>= 1) mm = fmaxf(mm, __shfl_xor(mm, off));
            mm = fmaxf(mm, -1000.0f);
            float e = (lv == -INFINITY) ? 0.f : __expf(lv - mm);
            float dd = e;
            for (int off = 32; off; off >>= 1) dd += __shfl_xor(dd, off);
            dd += __expf(-1000.0f - mm);
            float val = e / dd;
            float vc = val;
            int base = (kh * S + s) * 9;
            for (int t8 = 0; t8 < 8; ++t8) {
                float bv2 = vc; int bi = l;
                for (int off = 32; off; off >>= 1) {
                    float ov = __shfl_xor(bv2, off); int oi = __shfl_xor(bi, off);
                    if (ov > bv2 || (ov == bv2 && oi < bi)) { bv2 = ov; bi = oi; }
                }
                if (l == 0) sel[base + t8] = (bv2 > 1e-10f) ? bi : -1;
                if (l == bi) vc = -1.f;
            }
            if (l == 0) sel[base + 8] = s >> 5;
        }
    }
}

// ------------- fine + sliding attention (MFMA, swapped operands) -------------
// blockIdx.y==0: fine; ==1: sliding. Block=(kh,s), 4 waves = 4 grouped queries.
// Per wave per 64-key chunk: S^T = mfma(A=K, B=Q_bcast) -> C rows=keys;
// softmax in C-layout (2 shfl_xor); P packed bf16 (v_cvt_pk_bf16_f32) to
// wave-private LDS row; O^T = mfma(A=V^T, B=P_bcast) with online rescale of
// the accumulator. q is pre-scaled by 1/8. All 16 MFMA N-cols are copies of
// this wave's g (B-frag is a broadcast read) -> no garbage-column hazards.
__global__ __launch_bounds__(256, 4) void k_swattn(
    const unsigned short* __restrict__ qr16, const unsigned short* __restrict__ kr16,
    const unsigned short* __restrict__ v16, const int* __restrict__ sel,
    float* __restrict__ fob, float* __restrict__ sob)
{
    int kh = blockIdx.x >> 11, s = blockIdx.x & 2047;
    bool fine = (blockIdx.y == 0);
    float* outp = fine ? fob : sob;
    int t = threadIdx.x, w = t >> 6, lane = t & 63, g = w;
    int q4 = lane >> 4, l15 = lane & 15, kb4 = q4 * 4;

    __shared__ __align__(16) unsigned char KL[64 * 128];     // swizzled [key][16B grp ^ (key&7)]
    __shared__ __align__(16) unsigned short VT[64][72];      // [d][key] bf16 (transposed V)
    __shared__ __align__(16) unsigned short qL16[4][64];     // per-g q (scaled bf16)
    __shared__ __align__(16) unsigned short pL[4][64];       // per-g P row, bf16

    qL16[g][lane] = qr16[(((size_t)kh * G + g) * S + s) * DH + lane];

    int own_t = s & 31;
    int base = (kh * S + s) * 9;
    float m_run = -INFINITY, l_run = 0.f;
    f32x4_t acco[4] = {};    // O^T accum: tile Mt rows d=Mt*16+kb4+reg (col copies)

    int lo = s - WIN; if (lo < 0) lo = 0;
    int nch = fine ? 5 : ((s - lo + 63) >> 6);   // sliding: chunks over [lo, s-1]

    for (int c = 0; c < nch; ++c) {
        int bA = 0, bB = 0, kb = 0;
        bool vA, vB;
        if (fine) {
            bA = sel[base + c * 2];
            bB = (c < 4) ? sel[base + c * 2 + 1] : -1;
            if (bA < 0 && bB < 0) continue;   // uniform across block
            vA = bA >= 0; vB = bB >= 0;
        } else {
            kb = lo + c * 64; vA = true; vB = true;
        }
        __syncthreads();
        // ---- stage K (swizzled rows) and V^T (b16 scatter), zero-fill ----
        {
            int key = w * 16 + l15;
            int gkey; bool kv;
            if (fine) {
                int b = (key < 32) ? bA : bB;
                kv = b >= 0;
                gkey = (b < 0 ? 0 : b) * 32 + (key & 31);
            } else {
                gkey = kb + key;
                kv = gkey < s;            // diagonal key s handled separately
            }
            const uint4* kp = (const uint4*)&kr16[((size_t)kh * S + gkey) * DH];
            const uint4* vp = (const uint4*)&v16 [((size_t)kh * S + gkey) * DH];
            uint4 z = make_uint4(0, 0, 0, 0);
            #pragma unroll
            for (int i = 0; i < 2; ++i) {
                int grp = q4 + 4 * i;
                uint4 kd = kv ? kp[grp] : z;
                *(uint4*)(KL + key * 128 + 16 * (grp ^ (key & 7))) = kd;
                uint4 vd = kv ? vp[grp] : z;
                int d0 = grp * 8;
                unsigned int wd[4] = { vd.x, vd.y, vd.z, vd.w };
                #pragma unroll
                for (int jj = 0; jj < 4; ++jj) {
                    VT[d0 + 2 * jj][key]     = (unsigned short)(wd[jj] & 0xffffu);
                    VT[d0 + 2 * jj + 1][key] = (unsigned short)(wd[jj] >> 16);
                }
            }
        }
        __syncthreads();
        // ---- QK^T (swapped): S^T rows=keys, cols=copies of g ----
        bf16x8_t qb0 = *(const bf16x8_t*)((const unsigned char*)&qL16[w][0] + q4 * 16);
        bf16x8_t qb1 = *(const bf16x8_t*)((const unsigned char*)&qL16[w][0] + q4 * 16 + 64);
        f32x4_t accs[4] = {};
        #pragma unroll
        for (int Mt = 0; Mt < 4; ++Mt) {
            int key = Mt * 16 + l15;
            bf16x8_t a0 = *(const bf16x8_t*)(KL + key * 128 + 16 * ((q4    ) ^ (key & 7)));
            bf16x8_t a1 = *(const bf16x8_t*)(KL + key * 128 + 16 * ((q4 + 4) ^ (key & 7)));
            accs[Mt] = __builtin_amdgcn_mfma_f32_16x16x32_bf16(a0, qb0, accs[Mt], 0, 0, 0);
            accs[Mt] = __builtin_amdgcn_mfma_f32_16x16x32_bf16(a1, qb1, accs[Mt], 0, 0, 0);
        }
        // ---- masks + online softmax (C-layout: key = Mt*16 + kb4 + r) ----
        bool ownchunk = fine && (c == 4);
        float mx = -INFINITY;
        #pragma unroll
        for (int Mt = 0; Mt < 4; ++Mt)
        #pragma unroll
        for (int r = 0; r < 4; ++r) {
            int key = Mt * 16 + kb4 + r;
            bool valid;
            if (fine) valid = ((Mt < 2) ? vA : vB) && (!ownchunk || key <= own_t);
            else      valid = (kb + key) < s;
            float sv = valid ? accs[Mt][r] : -INFINITY;
            accs[Mt][r] = sv;
            mx = fmaxf(mx, sv);
        }
        mx = fmaxf(mx, __shfl_xor(mx, 16));
        mx = fmaxf(mx, __shfl_xor(mx, 32));
        float nm = fmaxf(m_run, mx);
        float alpha = __expf(m_run - nm);
        float ps = 0.f;
        #pragma unroll
        for (int Mt = 0; Mt < 4; ++Mt)
        #pragma unroll
        for (int r = 0; r < 4; ++r) {
            float pv = __expf(accs[Mt][r] - nm);
            accs[Mt][r] = pv;
            ps += pv;
        }
        ps += __shfl_xor(ps, 16);
        ps += __shfl_xor(ps, 32);
        l_run = l_run * alpha + ps;
        m_run = nm;
        #pragma unroll
        for (int Mt = 0; Mt < 4; ++Mt)
        #pragma unroll
        for (int r = 0; r < 4; ++r) acco[Mt][r] *= alpha;
        // ---- write P row (bf16) — lanes l15==0 cover all 64 keys ----
        if (l15 == 0) {
            #pragma unroll
            for (int Mt = 0; Mt < 4; ++Mt) {
                int k0 = Mt * 16 + kb4;
                unsigned int u0 = cvtpk_bf16(accs[Mt][0], accs[Mt][1]);
                unsigned int u1 = cvtpk_bf16(accs[Mt][2], accs[Mt][3]);
                *(unsigned int*)&pL[w][k0]     = u0;
                *(unsigned int*)&pL[w][k0 + 2] = u1;
            }
        }
        // ---- PV (swapped): O^T += mfma(A=V^T, B=P_bcast) ----
        bf16x8_t pb0 = *(const bf16x8_t*)&pL[w][q4 * 8];
        bf16x8_t pb1 = *(const bf16x8_t*)&pL[w][q4 * 8 + 32];
        #pragma unroll
        for (int Mt = 0; Mt < 4; ++Mt) {
            int d = Mt * 16 + l15;
            bf16x8_t va0 = *(const bf16x8_t*)&VT[d][q4 * 8];
            bf16x8_t va1 = *(const bf16x8_t*)&VT[d][q4 * 8 + 32];
            acco[Mt] = __builtin_amdgcn_mfma_f32_16x16x32_bf16(va0, pb0, acco[Mt], 0, 0, 0);
            acco[Mt] = __builtin_amdgcn_mfma_f32_16x16x32_bf16(va1, pb1, acco[Mt], 0, 0, 0);
        }
    }
    if (!fine) {
        // ---- diagonal key s: single online-softmax step ----
        float pr = bf2f(qL16[g][lane]) * bf2f(kr16[((size_t)kh * S + s) * DH + lane]);
        for (int off = 32; off; off >>= 1) pr += __shfl_xor(pr, off);
        float sim = pr;   // q pre-scaled
        float nm = fmaxf(m_run, sim);
        float alpha = __expf(m_run - nm);
        float p = __expf(sim - nm);
        l_run = l_run * alpha + p;
        #pragma unroll
        for (int Mt = 0; Mt < 4; ++Mt)
        #pragma unroll
        for (int r = 0; r < 4; ++r) acco[Mt][r] *= alpha;
        if (l15 == 0) {
            #pragma unroll
            for (int Mt = 0; Mt < 4; ++Mt) {
                uint2 v2 = *(const uint2*)&v16[((size_t)kh * S + s) * DH + Mt * 16 + kb4];
                acco[Mt][0] += p * bflo(v2.x);
                acco[Mt][1] += p * bfhi(v2.x);
                acco[Mt][2] += p * bflo(v2.y);
                acco[Mt][3] += p * bfhi(v2.y);
            }
        }
        m_run = nm;
    }
    // ---- output: lanes l15==0 hold O^T[d][g] for d = Mt*16 + kb4 + r ----
    if (l15 == 0) {
        float inv = 1.f / l_run;
        size_t ob = (((size_t)kh * G + g) * S + s) * DH;
        #pragma unroll
        for (int Mt = 0; Mt < 4; ++Mt) {
            float4 o = make_float4(acco[Mt][0] * inv, acco[Mt][1] * inv,
                                   acco[Mt][2] * inv, acco[Mt][3] * inv);
            *(float4*)&outp[ob + Mt * 16 + kb4] = o;
        }
    }
}

// ---------------- gates + combine -> bf16 ----------------
__global__ __launch_bounds__(256) void k_combine(
    const unsigned short* __restrict__ xbf, const float* __restrict__ comb_w, const float* __restrict__ comb_b,
    const float* __restrict__ c_out, const float* __restrict__ f_out, const float* __restrict__ s_out,
    unsigned short* __restrict__ comb)
{
    int s = blockIdx.x, t = threadIdx.x;
    __shared__ float gpart[24][8];
    __shared__ float gates[24];
    if (t < 192) {
        int cc = t >> 3, pt = t & 7;
        float sum = 0.f;
        for (int d = pt * 64; d < pt * 64 + 64; ++d)
            sum += bf2f(xbf[s * D + d]) * comb_w[d * 24 + cc];
        gpart[cc][pt] = sum;
    }
    __syncthreads();
    if (t < 24) {
        float sum = comb_b[t];
        for (int i = 0; i < 8; ++i) sum += gpart[t][i];
        gates[t] = 1.f / (1.f + __expf(-sum));
    }
    __syncthreads();
    for (int o = t; o < 512; o += 256) {
        int h = o >> 6, d = o & 63;
        int idx = (h * S + s) * DH + d;
        float r = gates[h * 3] * c_out[idx] + gates[h * 3 + 1] * f_out[idx] + gates[h * 3 + 2] * s_out[idx];
        comb[s * D + o] = f2bf(r);
    }
}

extern "C" void kernel_launch(void* const* d_in, const int* in_sizes, int n_in,
                              void* d_out, int out_size, void* d_ws, size_t ws_size,
                              hipStream_t stream)
{
    (void)in_sizes; (void)n_in; (void)out_size; (void)ws_size;
    const float* inp    = (const float*)d_in[0];
    const float* norm_w = (const float*)d_in[1];
    const float* w_qkv  = (const float*)d_in[2];
    const float* mem_kv = (const float*)d_in[3];
    const float* k_pos  = (const float*)d_in[4];
    const float* v_pos  = (const float*)d_in[5];
    const float* kc_w1  = (const float*)d_in[6];
    const float* kc_b1  = (const float*)d_in[7];
    const float* kc_w2  = (const float*)d_in[8];
    const float* kc_b2  = (const float*)d_in[9];
    const float* vc_w1  = (const float*)d_in[10];
    const float* vc_b1  = (const float*)d_in[11];
    const float* vc_w2  = (const float*)d_in[12];
    const float* vc_b2  = (const float*)d_in[13];
    const float* comb_w = (const float*)d_in[14];
    const float* comb_b = (const float*)d_in[15];
    const float* out_w  = (const float*)d_in[16];
    float* out = (float*)d_out;

    char* w = (char*)d_ws;
    size_t off = 0;
    auto alloc = [&](size_t bytes) { void* p = w + off; off += (bytes + 255) & ~(size_t)255; return p; };
    unsigned short* xbf   = (unsigned short*)alloc((size_t)S * D * 2);
    unsigned short* kbvb  = (unsigned short*)alloc((size_t)256 * 2048 * 2);
    unsigned short* hid   = (unsigned short*)alloc((size_t)256 * 2048 * 2);
    unsigned short* combb = (unsigned short*)alloc((size_t)S * 512 * 2);
    unsigned short* qr16  = (unsigned short*)alloc((size_t)H * S * DH * 2);
    unsigned short* kr16  = (unsigned short*)alloc((size_t)KH * S * DH * 2);
    unsigned short* v16   = (unsigned short*)alloc((size_t)KH * S * DH * 2);
    float* qb   = (float*)alloc((size_t)H * S * DH * 4);
    float* kbuf = (float*)alloc((size_t)KH * S * DH * 4);
    float* vbuf = (float*)alloc((size_t)KH * S * DH * 4);
    float* ckb  = (float*)alloc((size_t)KH * 65 * 64 * 4);
    float* cvb  = (float*)alloc((size_t)KH * 65 * 64 * 4);
    float* cob  = (float*)alloc((size_t)H * S * DH * 4);
    float* fob  = (float*)alloc((size_t)H * S * DH * 4);
    float* sob  = (float*)alloc((size_t)H * S * DH * 4);
    float* ctab = (float*)alloc((size_t)S * 32 * 4);
    float* stab = (float*)alloc((size_t)S * 32 * 4);
    int*   selb = (int*)alloc((size_t)KH * S * 9 * 4);

    // RMSNorm
    k_rmsnorm<<<S, 256, 0, stream>>>(inp, norm_w, xbf);

    // QKV projection
    k_gemm<0><<<dim3(768 / 64, S / 64), 256, 0, stream>>>(
        xbf, w_qkv, nullptr, nullptr, nullptr, S, 768, 512,
        qb, kbuf, vbuf, nullptr, nullptr);

    // compress MLP layer 1
    k_build_kbvb<<<(256 * 2048) / 256, 256, 0, stream>>>(kbuf, vbuf, k_pos, v_pos, kbvb);
    k_gemm<1><<<dim3(2048 / 64, 256 / 64), 256, 0, stream>>>(
        kbvb, kc_w1, vc_w1, kc_b1, vc_b1, 256, 2048, 2048,
        nullptr, nullptr, nullptr, hid, nullptr);

    // compress MLP layer 2 (MFMA) + mem row
    k_mem_init<<<1, 256, 0, stream>>>(mem_kv, ckb, cvb);
    k_gemm<3><<<dim3(1, 4), 256, 0, stream>>>(
        hid, kc_w2, vc_w2, kc_b2, vc_b2, 256, 64, 2048,
        ckb, cvb, nullptr, nullptr, nullptr);

    // RoPE tables + fused rope(q)*scale / rope(k) / convert(v)
    k_rope_table<<<(S * 32) / 256, 256, 0, stream>>>(ctab, stab);
    k_ropeprep<<<((H + 2 * KH) * S * 32) / 256, 256, 0, stream>>>(
        qb, kbuf, vbuf, ctab, stab, qr16, kr16, v16);

    // compressed attention + importance + top-8 selection
    k_cattn<<<KH * 256, 256, 0, stream>>>(qb, ckb, cvb, cob, selb);

    // fine + sliding attention (merged dispatch, MFMA)
    k_swattn<<<dim3(KH * S, 2), 256, 0, stream>>>(qr16, kr16, v16, selb, fob, sob);

    // gated combine + output projection
    k_combine<<<S, 256, 0, stream>>>(xbf, comb_w, comb_b, cob, fob, sob, combb);
    k_gemm<2><<<dim3(512 / 64, S / 64), 256, 0, stream>>>(
        combb, out_w, nullptr, nullptr, nullptr, S, 512, 512,
        nullptr, nullptr, nullptr, nullptr, out);
}

// Round 6
// 320.504 us; speedup vs baseline: 1.1419x; 1.1419x over previous
//
#include <hip/hip_runtime.h>
#include <hip/hip_bf16.h>
#include <math.h>

#define S 2048
#define D 512
#define H 8
#define KH 2
#define DH 64
#define G 4
#define CBS 32
#define NSEL 8
#define WIN 128
#define NC 64
#define CDIM 2048

typedef __attribute__((ext_vector_type(8))) short bf16x8_t;
typedef __attribute__((ext_vector_type(4))) float f32x4_t;
typedef __attribute__((ext_vector_type(2))) _Float16 half2v;

static __device__ __forceinline__ unsigned short f2bf(float f) {
    union { float f; unsigned int u; } v; v.f = f;
    unsigned int r = (v.u + 0x7FFFu + ((v.u >> 16) & 1u)) >> 16;
    return (unsigned short)r;
}
static __device__ __forceinline__ float bf2f(unsigned short h) {
    union { unsigned int u; float f; } v; v.u = ((unsigned int)h) << 16;
    return v.f;
}
static __device__ __forceinline__ float bflo(unsigned int u) {
    union { unsigned int u; float f; } v; v.u = u << 16; return v.f;
}
static __device__ __forceinline__ float bfhi(unsigned int u) {
    union { unsigned int u; float f; } v; v.u = u & 0xffff0000u; return v.f;
}
static __device__ __forceinline__ unsigned short f2h(float f) {
    union { _Float16 h; unsigned short s; } v; v.h = (_Float16)f; return v.s;
}
static __device__ __forceinline__ float h2f(unsigned short u) {
    union { unsigned short s; _Float16 h; } v; v.s = u; return (float)v.h;
}
// v_dot2_f32_f16: c += a.x*b.x + a.y*b.y  (f16 inputs, f32 accumulate)
static __device__ __forceinline__ float dot2f16(unsigned int a, unsigned int b, float c) {
    union { unsigned int u; half2v h; } A, B; A.u = a; B.u = b;
    return __builtin_amdgcn_fdot2(A.h, B.h, c, false);
}

// ---------------- RMSNorm -> x bf16 ----------------
__global__ __launch_bounds__(256) void k_rmsnorm(const float* __restrict__ inp,
                                                 const float* __restrict__ w,
                                                 unsigned short* __restrict__ xbf) {
    int s = blockIdx.x; int t = threadIdx.x;
    const float* row = inp + (size_t)s * D;
    float a = row[t], b = row[t + 256];
    float ss = a * a + b * b;
    for (int off = 32; off; off >>= 1) ss += __shfl_xor(ss, off);
    __shared__ float red[4];
    if ((t & 63) == 0) red[t >> 6] = ss;
    __syncthreads();
    float tot = red[0] + red[1] + red[2] + red[3];
    float inv = rsqrtf(tot / (float)D + 1.1920929e-07f);
    xbf[(size_t)s * D + t]       = f2bf(a * inv * w[t]);
    xbf[(size_t)s * D + t + 256] = f2bf(b * inv * w[t + 256]);
}

// ---------------- generic bf16 MFMA GEMM 64x64 tile ----------------
// A bf16; B weights f32, converted during LDS staging.
// MODE 0: qkv scatter. MODE 1: +bias, relu, bf16 (hid). MODE 2: fp32 out.
// MODE 3: +bias, scatter into ck/cv rows; block y==0 also writes mem_kv row 0
//         (vv carries mem_kv).
template<int MODE>
__global__ __launch_bounds__(256) void k_gemm(
    const unsigned short* __restrict__ A,
    const float* __restrict__ B0,
    const float* __restrict__ B1,
    const float* __restrict__ bias0, const float* __restrict__ bias1,
    int M, int N, int K,
    float* __restrict__ q, float* __restrict__ kk, float* __restrict__ vv,
    unsigned short* __restrict__ hid, float* __restrict__ outC)
{
    __shared__ __align__(16) unsigned short As[64][40];
    __shared__ __align__(16) unsigned short Bs[64][40];
    int t = threadIdx.x;
    int m0 = blockIdx.y * 64, n0 = blockIdx.x * 64;
    const float* W = B0;
    const float* bias = bias0;
    if ((MODE == 1 || MODE == 3) && blockIdx.y >= 2) { W = B1; bias = bias1; }
    if (MODE == 3 && blockIdx.y == 0) {
        // fold in mem_kv -> ck/cv row 0 (exactly 256 elements)
        int path2 = t >> 7, khm = (t >> 6) & 1, dm = t & 63;
        float* dstm = path2 ? kk : q;
        dstm[khm * 65 * 64 + dm] = vv[path2 * (KH * DH) + khm * DH + dm];
    }
    int wave = t >> 6, lane = t & 63;
    int mh = wave & 1, nh = wave >> 1;
    f32x4_t acc[2][2] = {};
    int ar = t >> 2, ac = (t & 3) * 8;
    int bk = t >> 3, bn = (t & 7) * 8;
    int arow_l = lane & 15, kcol = (lane >> 4) * 8;
    for (int k0 = 0; k0 < K; k0 += 32) {
        __syncthreads();
        *(uint4*)&As[ar][ac] = *(const uint4*)&A[(size_t)(m0 + ar) * K + k0 + ac];
        const float4* wrow = (const float4*)&W[(size_t)(k0 + bk) * N + n0 + bn];
        float4 w0 = wrow[0], w1 = wrow[1];
        unsigned short bp[8];
        bp[0] = f2bf(w0.x); bp[1] = f2bf(w0.y); bp[2] = f2bf(w0.z); bp[3] = f2bf(w0.w);
        bp[4] = f2bf(w1.x); bp[5] = f2bf(w1.y); bp[6] = f2bf(w1.z); bp[7] = f2bf(w1.w);
        #pragma unroll
        for (int j = 0; j < 8; ++j) Bs[bn + j][bk] = bp[j];
        __syncthreads();
        bf16x8_t a0 = *(const bf16x8_t*)&As[mh * 32 + arow_l][kcol];
        bf16x8_t a1 = *(const bf16x8_t*)&As[mh * 32 + 16 + arow_l][kcol];
        bf16x8_t b0v = *(const bf16x8_t*)&Bs[nh * 32 + arow_l][kcol];
        bf16x8_t b1v = *(const bf16x8_t*)&Bs[nh * 32 + 16 + arow_l][kcol];
        acc[0][0] = __builtin_amdgcn_mfma_f32_16x16x32_bf16(a0, b0v, acc[0][0], 0, 0, 0);
        acc[0][1] = __builtin_amdgcn_mfma_f32_16x16x32_bf16(a0, b1v, acc[0][1], 0, 0, 0);
        acc[1][0] = __builtin_amdgcn_mfma_f32_16x16x32_bf16(a1, b0v, acc[1][0], 0, 0, 0);
        acc[1][1] = __builtin_amdgcn_mfma_f32_16x16x32_bf16(a1, b1v, acc[1][1], 0, 0, 0);
    }
    #pragma unroll
    for (int mi = 0; mi < 2; ++mi)
    #pragma unroll
    for (int ni = 0; ni < 2; ++ni)
    #pragma unroll
    for (int r = 0; r < 4; ++r) {
        int gm = m0 + mh * 32 + mi * 16 + (lane >> 4) * 4 + r;
        int gn = n0 + nh * 32 + ni * 16 + (lane & 15);
        float val = acc[mi][ni][r];
        if (MODE == 0) {
            if (gn < 512)      q [((gn >> 6) * S + gm) * DH + (gn & 63)] = val;
            else if (gn < 640) kk[(((gn - 512) >> 6) * S + gm) * DH + ((gn - 512) & 63)] = val;
            else               vv[(((gn - 640) >> 6) * S + gm) * DH + ((gn - 640) & 63)] = val;
        } else if (MODE == 1) {
            float h = val + bias[gn]; if (h < 0.f) h = 0.f;
            hid[(size_t)gm * N + gn] = f2bf(h);
        } else if (MODE == 3) {
            float h = val + bias[gn];
            float* dst = (gm >= 128) ? kk : q;   // cv : ck
            int kh2 = (gm >> 6) & 1, nc2 = gm & 63;
            dst[(kh2 * 65 + 1 + nc2) * 64 + gn] = h;
        } else {
            outC[(size_t)gm * N + gn] = val;
        }
    }
}

// ---------------- kb/vb builder ----------------
__global__ void k_build_kbvb(const float* __restrict__ kbuf, const float* __restrict__ vbuf,
                             const float* __restrict__ k_pos, const float* __restrict__ v_pos,
                             unsigned short* __restrict__ kbvb) {
    int idx = blockIdx.x * 256 + threadIdx.x;   // 256*2048
    int r = idx >> 11, c = idx & 2047;
    int tt = c >> 6, dh = c & 63;
    int path = r >> 7, kh = (r >> 6) & 1, nc = r & 63;
    const float* src = path ? vbuf : kbuf;
    const float* pos = path ? v_pos : k_pos;
    float val = src[((kh * S) + nc * 32 + tt) * DH + dh] + pos[(kh * CBS + tt) * DH + dh];
    kbvb[idx] = f2bf(val);
}

// ------- fused rope(q), rope(k) -> fp16 ; convert(v) -> bf16 -------
// trig computed inline (table kernel folded in).
__global__ __launch_bounds__(256) void k_ropeprep(
    const float* __restrict__ qb, const float* __restrict__ kbuf, const float* __restrict__ vbuf,
    unsigned short* __restrict__ qr16, unsigned short* __restrict__ kr16,
    unsigned short* __restrict__ v16)
{
    int idx = blockIdx.x * 256 + threadIdx.x;   // (H*S + 2*KH*S) * 32
    int row = idx >> 5, p = idx & 31;
    const int QR = H * S, KR = KH * S;
    const float* src; unsigned short* dst; bool dorope;
    if (row < QR)           { src = qb   + (size_t)row * 64;             dst = qr16 + (size_t)row * 64;             dorope = true; }
    else if (row < QR + KR) { src = kbuf + (size_t)(row - QR) * 64;      dst = kr16 + (size_t)(row - QR) * 64;      dorope = true; }
    else                    { src = vbuf + (size_t)(row - QR - KR) * 64; dst = v16  + (size_t)(row - QR - KR) * 64; dorope = false; }
    float x0 = src[2 * p], x1 = src[2 * p + 1];
    if (dorope) {
        int s = row & (S - 1);
        float inv = powf(10000.0f, -(float)p / 32.0f);
        float fr = (float)s * inv;
        float c = cosf(fr), sn = sinf(fr);
        dst[2 * p]     = f2h(x0 * c - x1 * sn);
        dst[2 * p + 1] = f2h(x1 * c + x0 * sn);
    } else {
        dst[2 * p] = f2bf(x0); dst[2 * p + 1] = f2bf(x1);
    }
}

// ---------------- compressed attention + importance + top-8 ----------------
__global__ __launch_bounds__(256) void k_cattn(
    const float* __restrict__ q, const float* __restrict__ ck, const float* __restrict__ cv,
    float* __restrict__ c_out, int* __restrict__ sel)
{
    int kh = blockIdx.x >> 8, sc = blockIdx.x & 255;   // grid = 2*256
    int s_base = sc * 8;
    __shared__ float ckT[64][65];   // [d][j]
    __shared__ float cvL[64][66];   // [j][d]
    __shared__ float qL[4][64];
    __shared__ float simL[4][64];
    int t = threadIdx.x;
    for (int idx = t; idx < 4096; idx += 256) {
        int j = idx >> 6, d = idx & 63;
        ckT[d][j] = ck[(kh * 65 + j) * 64 + d];
        cvL[j][d] = cv[(kh * 65 + j) * 64 + d];
    }
    int g = t >> 6, lane = t & 63;
    for (int si = 0; si < 8; ++si) {
        int s = s_base + si;
        __syncthreads();
        qL[g][lane] = q[((kh * G + g) * S + s) * DH + lane];
        __syncthreads();
        int j = lane;
        bool valid = (j == 0) || (s >= j * 32);
        float sim = 0.f;
        #pragma unroll 8
        for (int d = 0; d < 64; ++d) sim += qL[g][d] * ckT[d][j];
        sim *= 0.125f;
        float simm = valid ? sim : -INFINITY;
        simL[g][j] = simm;
        float m = simm;
        for (int off = 32; off; off >>= 1) m = fmaxf(m, __shfl_xor(m, off));
        float p = valid ? __expf(simm - m) : 0.f;
        float den = p;
        for (int off = 32; off; off >>= 1) den += __shfl_xor(den, off);
        float pn = p / den;
        float acc = 0.f;
        #pragma unroll 8
        for (int jj = 0; jj < 64; ++jj)
            acc += __shfl(pn, jj) * cvL[jj][lane];
        c_out[((kh * G + g) * S + s) * DH + lane] = acc;
        __syncthreads();
        if (g == 0) {
            int l = lane;
            float lv = -INFINITY;
            if (l < 63 && s >= (l + 1) * 32)
                lv = 0.25f * (simL[0][l + 1] + simL[1][l + 1] + simL[2][l + 1] + simL[3][l + 1]);
            float mm = lv;
            for (int off = 32; off; off >>= 1) mm = fmaxf(mm, __shfl_xor(mm, off));
            mm = fmaxf(mm, -1000.0f);
            float e = (lv == -INFINITY) ? 0.f : __expf(lv - mm);
            float dd = e;
            for (int off = 32; off; off >>= 1) dd += __shfl_xor(dd, off);
            dd += __expf(-1000.0f - mm);
            float val = e / dd;
            float vc = val;
            int base = (kh * S + s) * 9;
            for (int t8 = 0; t8 < 8; ++t8) {
                float bv2 = vc; int bi = l;
                for (int off = 32; off; off >>= 1) {
                    float ov = __shfl_xor(bv2, off); int oi = __shfl_xor(bi, off);
                    if (ov > bv2 || (ov == bv2 && oi < bi)) { bv2 = ov; bi = oi; }
                }
                if (l == 0) sel[base + t8] = (bv2 > 1e-10f) ? bi : -1;
                if (l == bi) vc = -1.f;
            }
            if (l == 0) sel[base + 8] = s >> 5;
        }
    }
}

// ---------------- fine + sliding attention (SIMT, f16 q/k + v_dot2) ---------
// blockIdx.y==0: fine; ==1: sliding (full chunks over [lo,s-1] + inline diag).
// QK^T: lane = key, 32 v_dot2_f32_f16 in 4 independent chains (replaces 64
// unpack + 64 fma of the bf16 version). V stays bf16; PV unchanged.
// launch_bounds(256,4): VGPR cap 128 — a cap of 32 caused scratch spills.
__global__ __launch_bounds__(256, 4) void k_swattn(
    const unsigned short* __restrict__ qr16, const unsigned short* __restrict__ kr16,
    const unsigned short* __restrict__ v16, const int* __restrict__ sel,
    float* __restrict__ fob, float* __restrict__ sob)
{
    int kh = blockIdx.x >> 11, s = blockIdx.x & 2047;
    bool fine = (blockIdx.y == 0);
    float* outp = fine ? fob : sob;
    int t = threadIdx.x, w = t >> 6, lane = t & 63, g = w;
    __shared__ __align__(16) unsigned char KL[64 * 128];   // swizzled [key][grp^(key&7)]
    __shared__ __align__(16) unsigned char VL[64 * 144];   // [key][72 bf16]
    __shared__ unsigned short qL16[4][64];                  // wave-private (fp16)
    __shared__ float pL[4][64];                             // wave-private

    qL16[g][lane] = qr16[(((size_t)kh * G + g) * S + s) * DH + lane];

    int own_t = s & 31;
    int base = (kh * S + s) * 9;
    float m_run = -INFINITY, l_run = 0.f;
    float acc0 = 0.f, acc1 = 0.f;
    int h = lane >> 5, dhalf = lane & 31;

    int lo = s - WIN; if (lo < 0) lo = 0;
    int nch = fine ? 5 : ((s - lo + 63) >> 6);   // sliding: full chunks over [lo, s-1]

    for (int c = 0; c < nch; ++c) {
        int bA = 0, bB = 0, kb = 0;
        bool vA, vB;
        if (fine) {
            bA = sel[base + c * 2];
            bB = (c < 4) ? sel[base + c * 2 + 1] : -1;
            if (bA < 0 && bB < 0) continue;   // uniform across block
            vA = bA >= 0; vB = bB >= 0;
        } else {
            kb = lo + c * 64; vA = true; vB = true;
        }
        __syncthreads();
        // ---- stage K (swizzled) and V (row-major), zero-fill invalid ----
        {
            int key = w * 16 + (lane & 15);
            int gkey; bool kv;
            if (fine) {
                int b = (key < 32) ? bA : bB;
                kv = b >= 0;
                gkey = (b < 0 ? 0 : b) * 32 + (key & 31);
            } else {
                gkey = kb + key;
                kv = gkey < s;            // key s handled by diagonal path
            }
            const uint4* kp = (const uint4*)&kr16[((size_t)kh * S + gkey) * DH];
            const uint4* vp = (const uint4*)&v16 [((size_t)kh * S + gkey) * DH];
            uint4 z = make_uint4(0, 0, 0, 0);
            #pragma unroll
            for (int i = 0; i < 2; ++i) {
                int grp = (lane >> 4) + 4 * i;
                uint4 kd = kv ? kp[grp] : z;
                uint4 vd = kv ? vp[grp] : z;
                *(uint4*)(KL + key * 128 + 16 * (grp ^ (key & 7))) = kd;
                *(uint4*)(VL + key * 144 + 16 * grp) = vd;
            }
        }
        __syncthreads();
        // ---- QK^T: lane = key j, f16 dot2 ----
        int j = lane;
        bool valid;
        if (fine) {
            valid = (j < 32) ? vA : vB;
            if (c == 4) valid = valid && (j < 32) && (j <= own_t);
        } else {
            valid = (kb + j) < s;
        }
        float sva = 0.f, svb = 0.f, svc = 0.f, svd = 0.f;
        #pragma unroll
        for (int grp = 0; grp < 8; ++grp) {
            uint4 kk = *(const uint4*)(KL + j * 128 + 16 * (grp ^ (j & 7)));
            uint4 qq = *(const uint4*)((const unsigned char*)qL16 + g * 128 + 16 * grp);
            sva = dot2f16(kk.x, qq.x, sva);
            svb = dot2f16(kk.y, qq.y, svb);
            svc = dot2f16(kk.z, qq.z, svc);
            svd = dot2f16(kk.w, qq.w, svd);
        }
        float sv = (sva + svb) + (svc + svd);
        float sim = valid ? sv * 0.125f : -INFINITY;
        float cm = sim;
        for (int off = 32; off; off >>= 1) cm = fmaxf(cm, __shfl_xor(cm, off));
        float nm = fmaxf(m_run, cm);
        float alpha = __expf(m_run - nm);
        float p = valid ? __expf(sim - nm) : 0.f;
        float ps = p;
        for (int off = 32; off; off >>= 1) ps += __shfl_xor(ps, off);
        l_run = l_run * alpha + ps;
        pL[g][j] = p;                 // wave-private: no barrier needed
        m_run = nm;
        acc0 *= alpha; acc1 *= alpha;
        // ---- PV: lane owns dims (2*dhalf, 2*dhalf+1), key-half h ----
        bool hv = (h == 0) ? vA : vB;
        if (hv) {
            #pragma unroll
            for (int j4 = 0; j4 < 8; ++j4) {
                float4 p4 = *(const float4*)&pL[g][h * 32 + j4 * 4];
                const float* pp = (const float*)&p4;
                #pragma unroll
                for (int qq = 0; qq < 4; ++qq) {
                    unsigned int v2 = *(const unsigned int*)(VL + (h * 32 + j4 * 4 + qq) * 144 + 4 * dhalf);
                    acc0 += pp[qq] * bflo(v2);
                    acc1 += pp[qq] * bfhi(v2);
                }
            }
        }
    }
    if (!fine) {
        // ---- diagonal key s: single online-softmax step ----
        float pr = h2f(qL16[g][lane]) * h2f(kr16[((size_t)kh * S + s) * DH + lane]);
        for (int off = 32; off; off >>= 1) pr += __shfl_xor(pr, off);
        float sim = pr * 0.125f;
        float nm = fmaxf(m_run, sim);
        float alpha = __expf(m_run - nm);
        float p = __expf(sim - nm);
        l_run = l_run * alpha + p;
        acc0 *= alpha; acc1 *= alpha;
        if (h == 0) {
            unsigned int v2 = *(const unsigned int*)&v16[(((size_t)kh * S + s) * DH) + 2 * dhalf];
            acc0 += p * bflo(v2);
            acc1 += p * bfhi(v2);
        }
        m_run = nm;
    }
    acc0 += __shfl_xor(acc0, 32);
    acc1 += __shfl_xor(acc1, 32);
    if (lane < 32) {
        float inv = 1.f / l_run;
        float2 o2 = make_float2(acc0 * inv, acc1 * inv);
        *(float2*)&outp[(((size_t)kh * G + g) * S + s) * DH + 2 * dhalf] = o2;
    }
}

// ---------------- gates + combine -> bf16 ----------------
__global__ __launch_bounds__(256) void k_combine(
    const unsigned short* __restrict__ xbf, const float* __restrict__ comb_w, const float* __restrict__ comb_b,
    const float* __restrict__ c_out, const float* __restrict__ f_out, const float* __restrict__ s_out,
    unsigned short* __restrict__ comb)
{
    int s = blockIdx.x, t = threadIdx.x;
    __shared__ float gpart[24][8];
    __shared__ float gates[24];
    if (t < 192) {
        int cc = t >> 3, pt = t & 7;
        float sum = 0.f;
        for (int d = pt * 64; d < pt * 64 + 64; ++d)
            sum += bf2f(xbf[s * D + d]) * comb_w[d * 24 + cc];
        gpart[cc][pt] = sum;
    }
    __syncthreads();
    if (t < 24) {
        float sum = comb_b[t];
        for (int i = 0; i < 8; ++i) sum += gpart[t][i];
        gates[t] = 1.f / (1.f + __expf(-sum));
    }
    __syncthreads();
    for (int o = t; o < 512; o += 256) {
        int h = o >> 6, d = o & 63;
        int idx = (h * S + s) * DH + d;
        float r = gates[h * 3] * c_out[idx] + gates[h * 3 + 1] * f_out[idx] + gates[h * 3 + 2] * s_out[idx];
        comb[s * D + o] = f2bf(r);
    }
}

extern "C" void kernel_launch(void* const* d_in, const int* in_sizes, int n_in,
                              void* d_out, int out_size, void* d_ws, size_t ws_size,
                              hipStream_t stream)
{
    (void)in_sizes; (void)n_in; (void)out_size; (void)ws_size;
    const float* inp    = (const float*)d_in[0];
    const float* norm_w = (const float*)d_in[1];
    const float* w_qkv  = (const float*)d_in[2];
    const float* mem_kv = (const float*)d_in[3];
    const float* k_pos  = (const float*)d_in[4];
    const float* v_pos  = (const float*)d_in[5];
    const float* kc_w1  = (const float*)d_in[6];
    const float* kc_b1  = (const float*)d_in[7];
    const float* kc_w2  = (const float*)d_in[8];
    const float* kc_b2  = (const float*)d_in[9];
    const float* vc_w1  = (const float*)d_in[10];
    const float* vc_b1  = (const float*)d_in[11];
    const float* vc_w2  = (const float*)d_in[12];
    const float* vc_b2  = (const float*)d_in[13];
    const float* comb_w = (const float*)d_in[14];
    const float* comb_b = (const float*)d_in[15];
    const float* out_w  = (const float*)d_in[16];
    float* out = (float*)d_out;

    char* w = (char*)d_ws;
    size_t off = 0;
    auto alloc = [&](size_t bytes) { void* p = w + off; off += (bytes + 255) & ~(size_t)255; return p; };
    unsigned short* xbf   = (unsigned short*)alloc((size_t)S * D * 2);
    unsigned short* kbvb  = (unsigned short*)alloc((size_t)256 * 2048 * 2);
    unsigned short* hid   = (unsigned short*)alloc((size_t)256 * 2048 * 2);
    unsigned short* combb = (unsigned short*)alloc((size_t)S * 512 * 2);
    unsigned short* qr16  = (unsigned short*)alloc((size_t)H * S * DH * 2);
    unsigned short* kr16  = (unsigned short*)alloc((size_t)KH * S * DH * 2);
    unsigned short* v16   = (unsigned short*)alloc((size_t)KH * S * DH * 2);
    float* qb   = (float*)alloc((size_t)H * S * DH * 4);
    float* kbuf = (float*)alloc((size_t)KH * S * DH * 4);
    float* vbuf = (float*)alloc((size_t)KH * S * DH * 4);
    float* ckb  = (float*)alloc((size_t)KH * 65 * 64 * 4);
    float* cvb  = (float*)alloc((size_t)KH * 65 * 64 * 4);
    float* cob  = (float*)alloc((size_t)H * S * DH * 4);
    float* fob  = (float*)alloc((size_t)H * S * DH * 4);
    float* sob  = (float*)alloc((size_t)H * S * DH * 4);
    int*   selb = (int*)alloc((size_t)KH * S * 9 * 4);

    // RMSNorm
    k_rmsnorm<<<S, 256, 0, stream>>>(inp, norm_w, xbf);

    // QKV projection
    k_gemm<0><<<dim3(768 / 64, S / 64), 256, 0, stream>>>(
        xbf, w_qkv, nullptr, nullptr, nullptr, S, 768, 512,
        qb, kbuf, vbuf, nullptr, nullptr);

    // compress MLP layer 1
    k_build_kbvb<<<(256 * 2048) / 256, 256, 0, stream>>>(kbuf, vbuf, k_pos, v_pos, kbvb);
    k_gemm<1><<<dim3(2048 / 64, 256 / 64), 256, 0, stream>>>(
        kbvb, kc_w1, vc_w1, kc_b1, vc_b1, 256, 2048, 2048,
        nullptr, nullptr, nullptr, hid, nullptr);

    // compress MLP layer 2 (MFMA) + mem row (folded in)
    k_gemm<3><<<dim3(1, 4), 256, 0, stream>>>(
        hid, kc_w2, vc_w2, kc_b2, vc_b2, 256, 64, 2048,
        ckb, cvb, (float*)mem_kv, nullptr, nullptr);

    // fused rope(q)/rope(k) -> fp16, convert(v) -> bf16 (trig inline)
    k_ropeprep<<<((H + 2 * KH) * S * 32) / 256, 256, 0, stream>>>(
        qb, kbuf, vbuf, qr16, kr16, v16);

    // compressed attention + importance + top-8 selection
    k_cattn<<<KH * 256, 256, 0, stream>>>(qb, ckb, cvb, cob, selb);

    // fine + sliding attention (merged dispatch)
    k_swattn<<<dim3(KH * S, 2), 256, 0, stream>>>(qr16, kr16, v16, selb, fob, sob);

    // gated combine + output projection
    k_combine<<<S, 256, 0, stream>>>(xbf, comb_w, comb_b, cob, fob, sob, combb);
    k_gemm<2><<<dim3(512 / 64, S / 64), 256, 0, stream>>>(
        combb, out_w, nullptr, nullptr, nullptr, S, 512, 512,
        nullptr, nullptr, nullptr, nullptr, out);
}